// Round 12
// baseline (156.455 us; speedup 1.0000x reference)
//
#include <hip/hip_runtime.h>
#include <hip/hip_bf16.h>

#define NN 50000
#define RR 16
#define H0 128
#define H1 64
#define EE 800000
#define NBASE 8
#define NTILES (NN / 16)            // 3125
#define NGRPS ((NTILES + 3) / 4)    // 782 groups of 64 nodes
#define GEMM_BLOCKS (NGRPS * 2)     // 2 rels/wave -> 6256 wave-units
#define COUNT_BLOCKS ((EE + 255) / 256)  // 3125
#define NM (NN * RR)                // 800000 bins
#define NB1 782                     // scan1 blocks

typedef __attribute__((ext_vector_type(8))) short short8;
typedef __attribute__((ext_vector_type(4))) float f32x4;

__device__ inline short f2bs(float x) {
    __hip_bfloat16 b = __float2bfloat16(x);
    return *reinterpret_cast<short*>(&b);
}

// ---------------- prep: weights (blocks<512) + zero cnt ----------------
__global__ void k_prep(const float* __restrict__ comps, const float* __restrict__ bases,
                       __hip_bfloat16* __restrict__ wtT, int* __restrict__ cnt) {
    if (blockIdx.x < 512) {
        int idx = blockIdx.x * 256 + threadIdx.x;   // RR*H1*H0 = 131072 exactly
        int r = idx / (H1 * H0);
        int rem = idx % (H1 * H0);
        int o = rem / H0;
        int i = rem % H0;
        float acc = 0.0f;
#pragma unroll
        for (int b = 0; b < NBASE; ++b)
            acc += comps[r * NBASE + b] * bases[(b * H0 + i) * H1 + o];
        wtT[idx] = __float2bfloat16(acc);
    } else {
        int g = (blockIdx.x - 512) * 256 + threadIdx.x;
        if (g * 4 < NM) *(int4*)&cnt[g * 4] = (int4){0, 0, 0, 0};
    }
}

// ---------------- fused: [gemm blocks] + [count+rank blocks] ----------------
// gemm: wave owns 64 nodes x 2 rels (R12: split 4->2 rels for 2x TLP, with
// launch_bounds(256,1) keeping afrag(64)+acc(64) resident — R9's retry minus
// its confounders). Channel-permuted B tiles; lane (n16,kg) holds channels
// [kg*16,kg*16+16) of node n16; sector-complete stores (q0 -> row byte kg*16,
// q1 -> 64+kg*16). Row element ((l>>3)&1)*32+(l>>4)*8+(l&7) holds channel l.
// count: rank[e] = atomicAdd(cnt[s*16+r], 1); cnt ends as the histogram.
__global__ __launch_bounds__(256, 1)
void k_fused(const float* __restrict__ nodes,
             const __hip_bfloat16* __restrict__ wtT,
             __hip_bfloat16* __restrict__ nw,
             const int* __restrict__ src, const int* __restrict__ rel,
             int* __restrict__ cnt, int* __restrict__ rank) {
    if (blockIdx.x < GEMM_BLOCKS) {
        int wid  = threadIdx.x >> 6;
        int lane = threadIdx.x & 63;
        int gw   = blockIdx.x * 4 + wid;         // wave-unit id in [0, 6256)
        int ngrp = gw >> 3;                      // 64-node group
        int rg   = gw & 7;                       // relation group (2 rels)
        int n16  = lane & 15;
        int kg   = lane >> 4;

        int ntl = NTILES - ngrp * 4;
        if (ntl > 4) ntl = 4;

        short8 afrag[4][4];
#pragma unroll
        for (int t = 0; t < 4; ++t) {
            if (t < ntl) {
                const float* ap = &nodes[(size_t)((ngrp * 4 + t) * 16 + n16) * H0 + kg * 8];
#pragma unroll
                for (int ks = 0; ks < 4; ++ks) {
                    float4 lo = *(const float4*)(ap + ks * 32);
                    float4 hi = *(const float4*)(ap + ks * 32 + 4);
                    short8 a;
                    a[0] = f2bs(lo.x); a[1] = f2bs(lo.y); a[2] = f2bs(lo.z); a[3] = f2bs(lo.w);
                    a[4] = f2bs(hi.x); a[5] = f2bs(hi.y); a[6] = f2bs(hi.z); a[7] = f2bs(hi.w);
                    afrag[t][ks] = a;
                }
            }
        }

        int chb = (n16 >> 2) * 16 + (n16 & 3);

        for (int r0 = 0; r0 < 2; ++r0) {
            int r = rg * 2 + r0;
            const __hip_bfloat16* wrr = &wtT[((size_t)r * H1 + chb) * H0 + kg * 8];
            f32x4 acc[4][4];
#pragma unroll
            for (int ot = 0; ot < 4; ++ot)
#pragma unroll
                for (int t = 0; t < 4; ++t) acc[ot][t] = (f32x4){0, 0, 0, 0};

#pragma unroll
            for (int ot = 0; ot < 4; ++ot) {
#pragma unroll
                for (int ks = 0; ks < 4; ++ks) {
                    short8 w = *(const short8*)(wrr + (size_t)(ot * 4) * H0 + ks * 32);
                    acc[ot][0] = __builtin_amdgcn_mfma_f32_16x16x32_bf16(w, afrag[0][ks], acc[ot][0], 0, 0, 0);
                    acc[ot][1] = __builtin_amdgcn_mfma_f32_16x16x32_bf16(w, afrag[1][ks], acc[ot][1], 0, 0, 0);
                    acc[ot][2] = __builtin_amdgcn_mfma_f32_16x16x32_bf16(w, afrag[2][ks], acc[ot][2], 0, 0, 0);
                    acc[ot][3] = __builtin_amdgcn_mfma_f32_16x16x32_bf16(w, afrag[3][ks], acc[ot][3], 0, 0, 0);
                }
            }

#pragma unroll
            for (int t = 0; t < 4; ++t) {
                if (t >= ntl) break;
                unsigned pk[8];
#pragma unroll
                for (int j = 0; j < 8; ++j) {
                    f32x4 a = acc[j >> 1][t];
                    float lo = a[(j & 1) * 2], hi = a[(j & 1) * 2 + 1];
                    pk[j] = (unsigned)(unsigned short)f2bs(lo) |
                            ((unsigned)(unsigned short)f2bs(hi) << 16);
                }
                uint4 q0; q0.x = pk[0]; q0.y = pk[1]; q0.z = pk[2]; q0.w = pk[3];
                uint4 q1; q1.x = pk[4]; q1.y = pk[5]; q1.z = pk[6]; q1.w = pk[7];
                char* rowp = (char*)nw +
                             ((size_t)r * NN + (size_t)ngrp * 64 + t * 16 + n16) * 128;
                *(uint4*)(rowp + kg * 16)      = q0;
                *(uint4*)(rowp + 64 + kg * 16) = q1;
            }
        }
    } else {
        int e = (blockIdx.x - GEMM_BLOCKS) * 256 + threadIdx.x;
        if (e < EE) {
            int bin = src[e] * RR + rel[e];
            rank[e] = atomicAdd(&cnt[bin], 1);
        }
    }
}

// ---------------- scan1: per-block exclusive scan (1024 bins/block) --------
__global__ void k_scan1(const int* __restrict__ cnt, int* __restrict__ base2,
                        int* __restrict__ bsums) {
    __shared__ int tmp[256];
    int tid = threadIdx.x;
    int g = blockIdx.x * 256 + tid;
    int4 v = {0, 0, 0, 0};
    if (g * 4 < NM) v = *(const int4*)&cnt[g * 4];
    int s = v.x + v.y + v.z + v.w;
    tmp[tid] = s;
    __syncthreads();
    for (int off = 1; off < 256; off <<= 1) {
        int t = (tid >= off) ? tmp[tid - off] : 0;
        __syncthreads();
        tmp[tid] += t;
        __syncthreads();
    }
    int excl = tmp[tid] - s;
    if (tid == 255) bsums[blockIdx.x] = tmp[255];
    if (g * 4 < NM) {
        int4 o;
        o.x = excl;
        o.y = excl + v.x;
        o.z = excl + v.x + v.y;
        o.w = excl + v.x + v.y + v.z;
        *(int4*)&base2[g * 4] = o;
    }
}

// ---------------- scan2: exclusive scan of 782 block sums ----------------
__global__ void k_scan2(const int* __restrict__ bsums, int* __restrict__ bsofs) {
    __shared__ int tmp[256];
    int t = threadIdx.x;
    int i0 = t * 4;
    int v0 = (i0 < NB1) ? bsums[i0] : 0;
    int v1 = (i0 + 1 < NB1) ? bsums[i0 + 1] : 0;
    int v2 = (i0 + 2 < NB1) ? bsums[i0 + 2] : 0;
    int v3 = (i0 + 3 < NB1) ? bsums[i0 + 3] : 0;
    int tot = v0 + v1 + v2 + v3;
    tmp[t] = tot;
    __syncthreads();
    for (int off = 1; off < 256; off <<= 1) {
        int x = (t >= off) ? tmp[t - off] : 0;
        __syncthreads();
        tmp[t] += x;
        __syncthreads();
    }
    int excl = tmp[t] - tot;
    if (i0 < NB1)     bsofs[i0]     = excl;
    if (i0 + 1 < NB1) bsofs[i0 + 1] = excl + v0;
    if (i0 + 2 < NB1) bsofs[i0 + 2] = excl + v0 + v1;
    if (i0 + 3 < NB1) bsofs[i0 + 3] = excl + v0 + v1 + v2;
}

// ---------------- place: pos = base2[bin] + bsofs[blk] + rank[e] ----------
__global__ void k_place(const int* __restrict__ src, const int* __restrict__ rel,
                        const int* __restrict__ dst, const int* __restrict__ base2,
                        const int* __restrict__ bsofs, const int* __restrict__ rank,
                        unsigned* __restrict__ recs) {
    int e = blockIdx.x * blockDim.x + threadIdx.x;
    if (e < EE) {
        int bin = src[e] * RR + rel[e];
        int pos = base2[bin] + bsofs[bin >> 10] + rank[e];
        recs[pos] = ((unsigned)rel[e] << 16) | (unsigned)dst[e];
    }
}

// ---------------- per-src accumulation: one wave per src, zero atomics -----
// nw rows channel-permuted: element ((l>>3)&1)*32+(l>>4)*8+(l&7) = channel l.
// val = 1/cnt via wave-private LDS inverse table (cnt = final histogram).
__global__ void k_accum(const int* __restrict__ cnt, const int* __restrict__ base2,
                        const int* __restrict__ bsofs, const unsigned* __restrict__ recs,
                        const __hip_bfloat16* __restrict__ nw, const float* __restrict__ bias,
                        float* __restrict__ out) {
    __shared__ float inv[4][16];
    int w = threadIdx.x >> 6;
    int s = blockIdx.x * 4 + w;
    int lane = threadIdx.x & 63;
    if (s >= NN) return;
    if (lane < 16) inv[w][lane] = 1.0f / (float)cnt[s * RR + lane];
    int pl = ((lane >> 3) & 1) * 32 + (lane >> 4) * 8 + (lane & 7);
    int i0 = s * RR;
    int b0 = base2[i0] + bsofs[i0 >> 10];
    int b1 = (s == NN - 1) ? EE : base2[i0 + RR] + bsofs[(i0 + RR) >> 10];
    int n = b1 - b0;
    float a0 = bias[lane], a1 = 0.0f, a2 = 0.0f, a3 = 0.0f;
    int i = 0;
    for (; i + 4 <= n; i += 4) {
        unsigned rec0 = recs[b0 + i], rec1 = recs[b0 + i + 1];
        unsigned rec2 = recs[b0 + i + 2], rec3 = recs[b0 + i + 3];
        int r0 = rec0 >> 16, d0 = rec0 & 0xFFFF;
        int r1 = rec1 >> 16, d1 = rec1 & 0xFFFF;
        int r2 = rec2 >> 16, d2 = rec2 & 0xFFFF;
        int r3 = rec3 >> 16, d3 = rec3 & 0xFFFF;
        float m0 = __bfloat162float(nw[((size_t)r0 * NN + d0) * H1 + pl]);
        float m1 = __bfloat162float(nw[((size_t)r1 * NN + d1) * H1 + pl]);
        float m2 = __bfloat162float(nw[((size_t)r2 * NN + d2) * H1 + pl]);
        float m3 = __bfloat162float(nw[((size_t)r3 * NN + d3) * H1 + pl]);
        a0 += inv[w][r0] * m0;
        a1 += inv[w][r1] * m1;
        a2 += inv[w][r2] * m2;
        a3 += inv[w][r3] * m3;
    }
    for (; i < n; ++i) {
        unsigned rec = recs[b0 + i];
        int r = rec >> 16, d = rec & 0xFFFF;
        a0 += inv[w][r] * __bfloat162float(nw[((size_t)r * NN + d) * H1 + pl]);
    }
    out[(size_t)s * H1 + lane] = (a0 + a1) + (a2 + a3);
}

// ---------------- fallback (small ws) ----------------
__global__ void k_init_out(float* __restrict__ out, const float* __restrict__ bias) {
    int i = blockIdx.x * blockDim.x + threadIdx.x;
    if (i < NN * H1) out[i] = bias[i & (H1 - 1)];
}

__global__ void k_count_only(const int* __restrict__ src, const int* __restrict__ rel,
                             float* __restrict__ counts) {
    int e = blockIdx.x * blockDim.x + threadIdx.x;
    if (e < EE) atomicAdd(&counts[rel[e] * NN + src[e]], 1.0f);
}

__global__ void k_weights_fb(const float* __restrict__ comps, const float* __restrict__ bases,
                             __hip_bfloat16* __restrict__ wtT) {
    int idx = blockIdx.x * blockDim.x + threadIdx.x;
    if (idx >= RR * H1 * H0) return;
    int r = idx / (H1 * H0);
    int rem = idx % (H1 * H0);
    int o = rem / H0;
    int i = rem % H0;
    float acc = 0.0f;
#pragma unroll
    for (int b = 0; b < NBASE; ++b)
        acc += comps[r * NBASE + b] * bases[(b * H0 + i) * H1 + o];
    wtT[idx] = __float2bfloat16(acc);
}

__global__ void k_fused_edge(const int* __restrict__ src, const int* __restrict__ rel,
                             const int* __restrict__ dst, const float* __restrict__ nodes,
                             const float* __restrict__ counts,
                             const __hip_bfloat16* __restrict__ wtT, float* __restrict__ out) {
    int e = blockIdx.x * (blockDim.x >> 6) + (threadIdx.x >> 6);
    int lane = threadIdx.x & 63;
    if (e >= EE) return;
    int s = src[e], r = rel[e], d = dst[e];
    float val = 1.0f / counts[r * NN + s];
    const __hip_bfloat16* w = &wtT[(size_t)(r * H1 + lane) * H0];
    const float* nd = &nodes[(size_t)d * H0];
    float acc = 0.0f;
#pragma unroll 8
    for (int i = 0; i < H0; ++i) acc += nd[i] * __bfloat162float(w[i]);
    atomicAdd(&out[s * H1 + lane], acc * val);
}

extern "C" void kernel_launch(void* const* d_in, const int* in_sizes, int n_in,
                              void* d_out, int out_size, void* d_ws, size_t ws_size,
                              hipStream_t stream) {
    const float* nodes = (const float*)d_in[0];
    const float* comps = (const float*)d_in[1];
    const float* bases = (const float*)d_in[2];
    const float* bias  = (const float*)d_in[3];
    const int*   src   = (const int*)d_in[4];
    const int*   rel   = (const int*)d_in[5];
    const int*   dst   = (const int*)d_in[6];
    float* out = (float*)d_out;

    char* ws = (char*)d_ws;
    // ws layout (bytes), all 256-aligned, nw 128-aligned:
    //   cnt    i32 [NM]       @ 0           (3,200,000)
    //   base2  i32 [NM]       @ 3,200,256   (3,200,000)
    //   bsums  i32 [800]      @ 6,400,512
    //   bsofs  i32 [800]      @ 6,403,968
    //   wtT    bf16 [R*H1*H0] @ 6,407,424   (262,144)
    //   rank   i32 [EE]       @ 6,669,824   (3,200,000)
    //   recs   u32 [EE]       @ 9,870,080   (3,200,000)
    //   nw     bf16 [R*N*H1]  @ 13,070,080  (102,400,000) -> total 115,470,080
    int*   cnt           = (int*)ws;
    int*   base2         = (int*)(ws + 3200256);
    int*   bsums         = (int*)(ws + 6400512);
    int*   bsofs         = (int*)(ws + 6403968);
    __hip_bfloat16* wtT  = (__hip_bfloat16*)(ws + 6407424);
    int*   rank          = (int*)(ws + 6669824);
    unsigned* recs       = (unsigned*)(ws + 9870080);
    __hip_bfloat16* nw   = (__hip_bfloat16*)(ws + 13070080);
    const size_t need_full = 13070080ull + (size_t)RR * NN * H1 * 2ull;

    if (ws_size >= need_full) {
        k_prep<<<512 + 782, 256, 0, stream>>>(comps, bases, wtT, cnt);
        k_fused<<<GEMM_BLOCKS + COUNT_BLOCKS, 256, 0, stream>>>(nodes, wtT, nw, src, rel, cnt, rank);
        k_scan1<<<NB1, 256, 0, stream>>>(cnt, base2, bsums);
        k_scan2<<<1, 256, 0, stream>>>(bsums, bsofs);
        k_place<<<(EE + 255) / 256, 256, 0, stream>>>(src, rel, dst, base2, bsofs, rank, recs);
        k_accum<<<(NN + 3) / 4, 256, 0, stream>>>(cnt, base2, bsofs, recs, nw, bias, out);
    } else {
        float* countsF = (float*)ws;
        __hip_bfloat16* wtT2 = (__hip_bfloat16*)(ws + 3200256);
        (void)hipMemsetAsync(countsF, 0, (size_t)NM * 4, stream);
        k_count_only<<<(EE + 255) / 256, 256, 0, stream>>>(src, rel, countsF);
        k_weights_fb<<<(RR * H1 * H0 + 255) / 256, 256, 0, stream>>>(comps, bases, wtT2);
        k_init_out<<<(NN * H1 + 255) / 256, 256, 0, stream>>>(out, bias);
        k_fused_edge<<<EE / 4, 256, 0, stream>>>(src, rel, dst, nodes, countsF, wtT2, out);
    }
}

// Round 13
// 128.626 us; speedup vs baseline: 1.2164x; 1.2164x over previous
//
#include <hip/hip_runtime.h>
#include <hip/hip_bf16.h>

#define NN 50000
#define RR 16
#define H0 128
#define H1 64
#define EE 800000
#define NBASE 8
#define NTILES (NN / 16)            // 3125
#define NGRPS ((NTILES + 3) / 4)    // 782 groups of 64 nodes
#define GEMM_BLOCKS NGRPS           // block = 1 node-group, 4 waves = 4 rel-groups
#define COUNT_BLOCKS ((EE + 255) / 256)  // 3125
#define NM (NN * RR)                // 800000 bins
#define NB1 782                     // scan1 blocks

typedef __attribute__((ext_vector_type(8))) short short8;
typedef __attribute__((ext_vector_type(4))) short short4v;
typedef __attribute__((ext_vector_type(4))) float f32x4;

__device__ inline short f2bs(float x) {
    __hip_bfloat16 b = __float2bfloat16(x);
    return *reinterpret_cast<short*>(&b);
}

// ---------------- prep: weights (blocks<512) + zero cnt ----------------
__global__ void k_prep(const float* __restrict__ comps, const float* __restrict__ bases,
                       __hip_bfloat16* __restrict__ wtT, int* __restrict__ cnt) {
    if (blockIdx.x < 512) {
        int idx = blockIdx.x * 256 + threadIdx.x;   // RR*H1*H0 = 131072 exactly
        int r = idx / (H1 * H0);
        int rem = idx % (H1 * H0);
        int o = rem / H0;
        int i = rem % H0;
        float acc = 0.0f;
#pragma unroll
        for (int b = 0; b < NBASE; ++b)
            acc += comps[r * NBASE + b] * bases[(b * H0 + i) * H1 + o];
        wtT[idx] = __float2bfloat16(acc);
    } else {
        int g = (blockIdx.x - 512) * 256 + threadIdx.x;
        if (g * 4 < NM) *(int4*)&cnt[g * 4] = (int4){0, 0, 0, 0};
    }
}

// ---------------- fused: [gemm blocks] + [count+rank blocks] ----------------
// gemm: block = 64-node group; its 4 waves are the 4 rel-groups. A-tile is
// cooperatively staged ONCE per block into LDS (f32->bf16 fused, XOR-swizzled
// 16B blocks so ds_read_b128 has only free 2-way aliasing), cutting per-wave
// global A traffic 4x vs R11. MFMA loop identical to R11: channel-permuted B
// tiles; lane (n16,kg) holds channels [kg*16,kg*16+16) of node n16;
// sector-complete stores. Row elem ((l>>3)&1)*32+(l>>4)*8+(l&7) = channel l.
// count: rank[e] = atomicAdd(cnt[s*16+r], 1); cnt ends as the histogram.
__global__ __launch_bounds__(256, 1)
void k_fused(const float* __restrict__ nodes,
             const __hip_bfloat16* __restrict__ wtT,
             __hip_bfloat16* __restrict__ nw,
             const int* __restrict__ src, const int* __restrict__ rel,
             int* __restrict__ cnt, int* __restrict__ rank) {
    __shared__ __hip_bfloat16 asmem[64 * 128];     // 16 KB staged A-tile
    if (blockIdx.x < GEMM_BLOCKS) {
        int tid  = threadIdx.x;
        int ngrp = blockIdx.x;
        int ntl = NTILES - ngrp * 4;
        if (ntl > 4) ntl = 4;

        // coop stage: 8 iters x float4 (4KB/iter, fully coalesced), f32->bf16,
        // swizzled 8B LDS writes (2-way bank aliasing = free).
#pragma unroll
        for (int i = 0; i < 8; ++i) {
            int f = i * 256 + tid;                 // float4 idx in 64x128 f32 tile
            int row = f >> 5;                      // 32 float4 per row
            int chunk = f & 31;
            int node = ngrp * 64 + row;
            if (node > NN - 1) node = NN - 1;      // clamp (rows >= ntl*16 unused)
            float4 v = *(const float4*)&nodes[(size_t)node * H0 + chunk * 4];
            short4v o;
            o[0] = f2bs(v.x); o[1] = f2bs(v.y); o[2] = f2bs(v.z); o[3] = f2bs(v.w);
            int blk = chunk >> 1, half = chunk & 1;
            *(short4v*)((char*)asmem + row * 256 + ((blk ^ (row & 7)) << 4) + half * 8) = o;
        }
        __syncthreads();

        int wid  = tid >> 6;
        int lane = tid & 63;
        int rg   = wid;                            // rel-group (4 rels)
        int n16  = lane & 15;
        int kg   = lane >> 4;

        // A fragments from LDS (register-resident across all 4 rels)
        short8 afrag[4][4];
#pragma unroll
        for (int t = 0; t < 4; ++t) {
            if (t < ntl) {
                int r = t * 16 + n16;
#pragma unroll
                for (int ks = 0; ks < 4; ++ks)
                    afrag[t][ks] = *(const short8*)((char*)asmem + r * 256 +
                                                    (((ks * 4 + kg) ^ (n16 & 7)) << 4));
            }
        }

        int chb = (n16 >> 2) * 16 + (n16 & 3);

        for (int r0 = 0; r0 < 4; ++r0) {
            int r = rg * 4 + r0;
            const __hip_bfloat16* wrr = &wtT[((size_t)r * H1 + chb) * H0 + kg * 8];
            f32x4 acc[4][4];
#pragma unroll
            for (int ot = 0; ot < 4; ++ot)
#pragma unroll
                for (int t = 0; t < 4; ++t) acc[ot][t] = (f32x4){0, 0, 0, 0};

#pragma unroll
            for (int ot = 0; ot < 4; ++ot) {
#pragma unroll
                for (int ks = 0; ks < 4; ++ks) {
                    short8 w = *(const short8*)(wrr + (size_t)(ot * 4) * H0 + ks * 32);
                    acc[ot][0] = __builtin_amdgcn_mfma_f32_16x16x32_bf16(w, afrag[0][ks], acc[ot][0], 0, 0, 0);
                    acc[ot][1] = __builtin_amdgcn_mfma_f32_16x16x32_bf16(w, afrag[1][ks], acc[ot][1], 0, 0, 0);
                    acc[ot][2] = __builtin_amdgcn_mfma_f32_16x16x32_bf16(w, afrag[2][ks], acc[ot][2], 0, 0, 0);
                    acc[ot][3] = __builtin_amdgcn_mfma_f32_16x16x32_bf16(w, afrag[3][ks], acc[ot][3], 0, 0, 0);
                }
            }

#pragma unroll
            for (int t = 0; t < 4; ++t) {
                if (t >= ntl) break;
                unsigned pk[8];
#pragma unroll
                for (int j = 0; j < 8; ++j) {
                    f32x4 a = acc[j >> 1][t];
                    float lo = a[(j & 1) * 2], hi = a[(j & 1) * 2 + 1];
                    pk[j] = (unsigned)(unsigned short)f2bs(lo) |
                            ((unsigned)(unsigned short)f2bs(hi) << 16);
                }
                uint4 q0; q0.x = pk[0]; q0.y = pk[1]; q0.z = pk[2]; q0.w = pk[3];
                uint4 q1; q1.x = pk[4]; q1.y = pk[5]; q1.z = pk[6]; q1.w = pk[7];
                char* rowp = (char*)nw +
                             ((size_t)r * NN + (size_t)ngrp * 64 + t * 16 + n16) * 128;
                *(uint4*)(rowp + kg * 16)      = q0;
                *(uint4*)(rowp + 64 + kg * 16) = q1;
            }
        }
    } else {
        int e = (blockIdx.x - GEMM_BLOCKS) * 256 + threadIdx.x;
        if (e < EE) {
            int bin = src[e] * RR + rel[e];
            rank[e] = atomicAdd(&cnt[bin], 1);
        }
    }
}

// ---------------- scan1: per-block exclusive scan (1024 bins/block) --------
__global__ void k_scan1(const int* __restrict__ cnt, int* __restrict__ base2,
                        int* __restrict__ bsums) {
    __shared__ int tmp[256];
    int tid = threadIdx.x;
    int g = blockIdx.x * 256 + tid;
    int4 v = {0, 0, 0, 0};
    if (g * 4 < NM) v = *(const int4*)&cnt[g * 4];
    int s = v.x + v.y + v.z + v.w;
    tmp[tid] = s;
    __syncthreads();
    for (int off = 1; off < 256; off <<= 1) {
        int t = (tid >= off) ? tmp[tid - off] : 0;
        __syncthreads();
        tmp[tid] += t;
        __syncthreads();
    }
    int excl = tmp[tid] - s;
    if (tid == 255) bsums[blockIdx.x] = tmp[255];
    if (g * 4 < NM) {
        int4 o;
        o.x = excl;
        o.y = excl + v.x;
        o.z = excl + v.x + v.y;
        o.w = excl + v.x + v.y + v.z;
        *(int4*)&base2[g * 4] = o;
    }
}

// ---------------- scan2: exclusive scan of 782 block sums ----------------
__global__ void k_scan2(const int* __restrict__ bsums, int* __restrict__ bsofs) {
    __shared__ int tmp[256];
    int t = threadIdx.x;
    int i0 = t * 4;
    int v0 = (i0 < NB1) ? bsums[i0] : 0;
    int v1 = (i0 + 1 < NB1) ? bsums[i0 + 1] : 0;
    int v2 = (i0 + 2 < NB1) ? bsums[i0 + 2] : 0;
    int v3 = (i0 + 3 < NB1) ? bsums[i0 + 3] : 0;
    int tot = v0 + v1 + v2 + v3;
    tmp[t] = tot;
    __syncthreads();
    for (int off = 1; off < 256; off <<= 1) {
        int x = (t >= off) ? tmp[t - off] : 0;
        __syncthreads();
        tmp[t] += x;
        __syncthreads();
    }
    int excl = tmp[t] - tot;
    if (i0 < NB1)     bsofs[i0]     = excl;
    if (i0 + 1 < NB1) bsofs[i0 + 1] = excl + v0;
    if (i0 + 2 < NB1) bsofs[i0 + 2] = excl + v0 + v1;
    if (i0 + 3 < NB1) bsofs[i0 + 3] = excl + v0 + v1 + v2;
}

// ---------------- place: pos = base2[bin] + bsofs[blk] + rank[e] ----------
__global__ void k_place(const int* __restrict__ src, const int* __restrict__ rel,
                        const int* __restrict__ dst, const int* __restrict__ base2,
                        const int* __restrict__ bsofs, const int* __restrict__ rank,
                        unsigned* __restrict__ recs) {
    int e = blockIdx.x * blockDim.x + threadIdx.x;
    if (e < EE) {
        int bin = src[e] * RR + rel[e];
        int pos = base2[bin] + bsofs[bin >> 10] + rank[e];
        recs[pos] = ((unsigned)rel[e] << 16) | (unsigned)dst[e];
    }
}

// ---------------- per-src accumulation: one wave per src, zero atomics -----
// nw rows channel-permuted: element ((l>>3)&1)*32+(l>>4)*8+(l&7) = channel l.
// val = 1/cnt via wave-private LDS inverse table (cnt = final histogram).
__global__ void k_accum(const int* __restrict__ cnt, const int* __restrict__ base2,
                        const int* __restrict__ bsofs, const unsigned* __restrict__ recs,
                        const __hip_bfloat16* __restrict__ nw, const float* __restrict__ bias,
                        float* __restrict__ out) {
    __shared__ float inv[4][16];
    int w = threadIdx.x >> 6;
    int s = blockIdx.x * 4 + w;
    int lane = threadIdx.x & 63;
    if (s >= NN) return;
    if (lane < 16) inv[w][lane] = 1.0f / (float)cnt[s * RR + lane];
    int pl = ((lane >> 3) & 1) * 32 + (lane >> 4) * 8 + (lane & 7);
    int i0 = s * RR;
    int b0 = base2[i0] + bsofs[i0 >> 10];
    int b1 = (s == NN - 1) ? EE : base2[i0 + RR] + bsofs[(i0 + RR) >> 10];
    int n = b1 - b0;
    float a0 = bias[lane], a1 = 0.0f, a2 = 0.0f, a3 = 0.0f;
    int i = 0;
    for (; i + 4 <= n; i += 4) {
        unsigned rec0 = recs[b0 + i], rec1 = recs[b0 + i + 1];
        unsigned rec2 = recs[b0 + i + 2], rec3 = recs[b0 + i + 3];
        int r0 = rec0 >> 16, d0 = rec0 & 0xFFFF;
        int r1 = rec1 >> 16, d1 = rec1 & 0xFFFF;
        int r2 = rec2 >> 16, d2 = rec2 & 0xFFFF;
        int r3 = rec3 >> 16, d3 = rec3 & 0xFFFF;
        float m0 = __bfloat162float(nw[((size_t)r0 * NN + d0) * H1 + pl]);
        float m1 = __bfloat162float(nw[((size_t)r1 * NN + d1) * H1 + pl]);
        float m2 = __bfloat162float(nw[((size_t)r2 * NN + d2) * H1 + pl]);
        float m3 = __bfloat162float(nw[((size_t)r3 * NN + d3) * H1 + pl]);
        a0 += inv[w][r0] * m0;
        a1 += inv[w][r1] * m1;
        a2 += inv[w][r2] * m2;
        a3 += inv[w][r3] * m3;
    }
    for (; i < n; ++i) {
        unsigned rec = recs[b0 + i];
        int r = rec >> 16, d = rec & 0xFFFF;
        a0 += inv[w][r] * __bfloat162float(nw[((size_t)r * NN + d) * H1 + pl]);
    }
    out[(size_t)s * H1 + lane] = (a0 + a1) + (a2 + a3);
}

// ---------------- fallback (small ws) ----------------
__global__ void k_init_out(float* __restrict__ out, const float* __restrict__ bias) {
    int i = blockIdx.x * blockDim.x + threadIdx.x;
    if (i < NN * H1) out[i] = bias[i & (H1 - 1)];
}

__global__ void k_count_only(const int* __restrict__ src, const int* __restrict__ rel,
                             float* __restrict__ counts) {
    int e = blockIdx.x * blockDim.x + threadIdx.x;
    if (e < EE) atomicAdd(&counts[rel[e] * NN + src[e]], 1.0f);
}

__global__ void k_weights_fb(const float* __restrict__ comps, const float* __restrict__ bases,
                             __hip_bfloat16* __restrict__ wtT) {
    int idx = blockIdx.x * blockDim.x + threadIdx.x;
    if (idx >= RR * H1 * H0) return;
    int r = idx / (H1 * H0);
    int rem = idx % (H1 * H0);
    int o = rem / H0;
    int i = rem % H0;
    float acc = 0.0f;
#pragma unroll
    for (int b = 0; b < NBASE; ++b)
        acc += comps[r * NBASE + b] * bases[(b * H0 + i) * H1 + o];
    wtT[idx] = __float2bfloat16(acc);
}

__global__ void k_fused_edge(const int* __restrict__ src, const int* __restrict__ rel,
                             const int* __restrict__ dst, const float* __restrict__ nodes,
                             const float* __restrict__ counts,
                             const __hip_bfloat16* __restrict__ wtT, float* __restrict__ out) {
    int e = blockIdx.x * (blockDim.x >> 6) + (threadIdx.x >> 6);
    int lane = threadIdx.x & 63;
    if (e >= EE) return;
    int s = src[e], r = rel[e], d = dst[e];
    float val = 1.0f / counts[r * NN + s];
    const __hip_bfloat16* w = &wtT[(size_t)(r * H1 + lane) * H0];
    const float* nd = &nodes[(size_t)d * H0];
    float acc = 0.0f;
#pragma unroll 8
    for (int i = 0; i < H0; ++i) acc += nd[i] * __bfloat162float(w[i]);
    atomicAdd(&out[s * H1 + lane], acc * val);
}

extern "C" void kernel_launch(void* const* d_in, const int* in_sizes, int n_in,
                              void* d_out, int out_size, void* d_ws, size_t ws_size,
                              hipStream_t stream) {
    const float* nodes = (const float*)d_in[0];
    const float* comps = (const float*)d_in[1];
    const float* bases = (const float*)d_in[2];
    const float* bias  = (const float*)d_in[3];
    const int*   src   = (const int*)d_in[4];
    const int*   rel   = (const int*)d_in[5];
    const int*   dst   = (const int*)d_in[6];
    float* out = (float*)d_out;

    char* ws = (char*)d_ws;
    // ws layout (bytes), all 256-aligned, nw 128-aligned:
    //   cnt    i32 [NM]       @ 0           (3,200,000)
    //   base2  i32 [NM]       @ 3,200,256   (3,200,000)
    //   bsums  i32 [800]      @ 6,400,512
    //   bsofs  i32 [800]      @ 6,403,968
    //   wtT    bf16 [R*H1*H0] @ 6,407,424   (262,144)
    //   rank   i32 [EE]       @ 6,669,824   (3,200,000)
    //   recs   u32 [EE]       @ 9,870,080   (3,200,000)
    //   nw     bf16 [R*N*H1]  @ 13,070,080  (102,400,000) -> total 115,470,080
    int*   cnt           = (int*)ws;
    int*   base2         = (int*)(ws + 3200256);
    int*   bsums         = (int*)(ws + 6400512);
    int*   bsofs         = (int*)(ws + 6403968);
    __hip_bfloat16* wtT  = (__hip_bfloat16*)(ws + 6407424);
    int*   rank          = (int*)(ws + 6669824);
    unsigned* recs       = (unsigned*)(ws + 9870080);
    __hip_bfloat16* nw   = (__hip_bfloat16*)(ws + 13070080);
    const size_t need_full = 13070080ull + (size_t)RR * NN * H1 * 2ull;

    if (ws_size >= need_full) {
        k_prep<<<512 + 782, 256, 0, stream>>>(comps, bases, wtT, cnt);
        k_fused<<<GEMM_BLOCKS + COUNT_BLOCKS, 256, 0, stream>>>(nodes, wtT, nw, src, rel, cnt, rank);
        k_scan1<<<NB1, 256, 0, stream>>>(cnt, base2, bsums);
        k_scan2<<<1, 256, 0, stream>>>(bsums, bsofs);
        k_place<<<(EE + 255) / 256, 256, 0, stream>>>(src, rel, dst, base2, bsofs, rank, recs);
        k_accum<<<(NN + 3) / 4, 256, 0, stream>>>(cnt, base2, bsofs, recs, nw, bias, out);
    } else {
        float* countsF = (float*)ws;
        __hip_bfloat16* wtT2 = (__hip_bfloat16*)(ws + 3200256);
        (void)hipMemsetAsync(countsF, 0, (size_t)NM * 4, stream);
        k_count_only<<<(EE + 255) / 256, 256, 0, stream>>>(src, rel, countsF);
        k_weights_fb<<<(RR * H1 * H0 + 255) / 256, 256, 0, stream>>>(comps, bases, wtT2);
        k_init_out<<<(NN * H1 + 255) / 256, 256, 0, stream>>>(out, bias);
        k_fused_edge<<<EE / 4, 256, 0, stream>>>(src, rel, dst, nodes, countsF, wtT2, out);
    }
}